// Round 8
// baseline (283.810 us; speedup 1.0000x reference)
//
#include <hip/hip_runtime.h>
#include <math.h>

// Problem constants
constexpr int NND = 8192;           // N nodes
constexpr int FD  = 512;            // features
constexpr int HD  = 128;            // hidden
constexpr int ED  = 262144;         // edges
constexpr long long NF_ = (long long)NND * FD;      // 4,194,304
constexpr long long NN_ = (long long)NND * NND;     // 67,108,864

// zero-fill quad partition of the dense adj region (units: float4 quads)
constexpr long long Z_K1 = 0;               // k1: 32 * 262144 = 8,388,608 (8/16)
constexpr long long Z_KD = 8388608;         // kD:  8 * 262144 = 2,097,152 (2/16)
constexpr long long Z_KE = 10485760;        // kE:  4 * 1048576 = 4,194,304 (4/16)
constexpr long long Z_KF = 14680064;        // kF:  8 * 262144 = 2,097,152 (ends 16,777,216)

constexpr int GEMMB = 512;                  // GEMM blocks (16 rows each), bids [1,513)
constexpr int FEAT_BASE = 1 + GEMMB;        // feature blocks start here (1024 of them)

// ctrl words: [4]=ticketF, [5]=ticketZ, [8..9]=float lo/hi (written by kF)

// K1: block 0 = LDS histogram of row[] -> counts + ctrl init;
//     blocks [1,513) = fp32 GEMM xw = x@W_enc (2 rows/thread, float4 x loads);
//     blocks [513,1537) = feature mask (4 quads/thread) + 8/16 adj fill.
__global__ __launch_bounds__(256) void k1_mega(const float* __restrict__ x,
                                               const float* __restrict__ W,
                                               const float* __restrict__ mask_u,
                                               const int* __restrict__ row,
                                               float* __restrict__ out,
                                               float* __restrict__ xw,
                                               int* __restrict__ counts,
                                               unsigned* __restrict__ ctrl) {
    __shared__ int hist[4096];      // 8192 packed 16-bit counters (16 KB)
    int tid = threadIdx.x;

    if (blockIdx.x == 0) {
        // ---- histogram block ----
        if (tid < 16) ctrl[tid] = 0u;
#pragma unroll
        for (int j = 0; j < 16; ++j) hist[tid + j * 256] = 0;
        __syncthreads();
        const int4* rq = (const int4*)row;
        for (int i = tid; i < ED / 4; i += 256) {
            int4 r4 = rq[i];
            atomicAdd(&hist[r4.x >> 1], 1 << ((r4.x & 1) * 16));
            atomicAdd(&hist[r4.y >> 1], 1 << ((r4.y & 1) * 16));
            atomicAdd(&hist[r4.z >> 1], 1 << ((r4.z & 1) * 16));
            atomicAdd(&hist[r4.w >> 1], 1 << ((r4.w & 1) * 16));
        }
        __syncthreads();
        // unpack: thread t owns hist ints [t*16, t*16+16) = rows [t*32, t*32+32)
#pragma unroll
        for (int j = 0; j < 16; ++j) {
            int pv = hist[tid * 16 + j];
            counts[tid * 32 + 2 * j]     = pv & 0xFFFF;
            counts[tid * 32 + 2 * j + 1] = pv >> 16;
        }
    } else if (blockIdx.x < FEAT_BASE) {
        // ---- GEMM: block = 16 rows x 128 cols; thread = 2 rows x 4 cols ----
        int bid = blockIdx.x - 1;
        int tx = tid & 31, ty = tid >> 5;
        int m0 = bid * 16 + ty * 2;
        const float* xr0 = x + (long long)m0 * FD;
        const float* xr1 = xr0 + FD;
        float a0[4] = {0.f, 0.f, 0.f, 0.f};
        float a1[4] = {0.f, 0.f, 0.f, 0.f};
        for (int k = 0; k < FD; k += 4) {
            float4 xa = *(const float4*)(xr0 + k);
            float4 xb = *(const float4*)(xr1 + k);
            float sa[4] = {xa.x, xa.y, xa.z, xa.w};
            float sb[4] = {xb.x, xb.y, xb.z, xb.w};
#pragma unroll
            for (int j = 0; j < 4; ++j) {
                float4 b = *(const float4*)(W + (k + j) * HD + tx * 4);
                a0[0] = fmaf(sa[j], b.x, a0[0]);
                a0[1] = fmaf(sa[j], b.y, a0[1]);
                a0[2] = fmaf(sa[j], b.z, a0[2]);
                a0[3] = fmaf(sa[j], b.w, a0[3]);
                a1[0] = fmaf(sb[j], b.x, a1[0]);
                a1[1] = fmaf(sb[j], b.y, a1[1]);
                a1[2] = fmaf(sb[j], b.z, a1[2]);
                a1[3] = fmaf(sb[j], b.w, a1[3]);
            }
        }
        *(float4*)(xw + (long long)m0 * HD + tx * 4) =
            make_float4(a0[0], a0[1], a0[2], a0[3]);
        *(float4*)(xw + (long long)(m0 + 1) * HD + tx * 4) =
            make_float4(a1[0], a1[1], a1[2], a1[3]);
    } else {
        int fid = (blockIdx.x - FEAT_BASE) * 256 + tid;   // 0 .. 262143
        // column-quad = fid & 127 (stride 262144 is a multiple of 128)
        int c4 = (fid & 127) * 4;
        float kx = (mask_u[c4 + 0] < 0.2f) ? 0.f : 1.f;
        float ky = (mask_u[c4 + 1] < 0.2f) ? 0.f : 1.f;
        float kz = (mask_u[c4 + 2] < 0.2f) ? 0.f : 1.f;
        float kw = (mask_u[c4 + 3] < 0.2f) ? 0.f : 1.f;
        const float4* xq = (const float4*)x;
        float4* oq = (float4*)out;
#pragma unroll
        for (int j = 0; j < 4; ++j) {
            long long q = fid + (long long)j * 262144;
            float4 xv = xq[q];
            float4 o;
            o.x = xv.x * kx; o.y = xv.y * ky; o.z = xv.z * kz; o.w = xv.w * kw;
            oq[q] = o;
        }
        // 8/16 of the dense adj zero-fill
        float4* zq = (float4*)(out + NF_);
        float4 z = make_float4(0.f, 0.f, 0.f, 0.f);
#pragma unroll
        for (int j = 0; j < 32; ++j)
            zq[Z_K1 + fid + (long long)j * 262144] = z;
    }
}

// K_C: exclusive scan of per-row counts -> row_start[N+1], cursor[N]. 1 block/256.
__global__ __launch_bounds__(256) void kC_scan(const int* __restrict__ counts,
                                               int* __restrict__ row_start,
                                               int* __restrict__ cursor) {
    __shared__ int ssc[256];
    int t = threadIdx.x;
    int c[32];
    int sum = 0;
    const int4* cp = (const int4*)counts;
#pragma unroll
    for (int j = 0; j < 8; ++j) {
        int4 vv = cp[t * 8 + j];
        c[j * 4 + 0] = vv.x; c[j * 4 + 1] = vv.y;
        c[j * 4 + 2] = vv.z; c[j * 4 + 3] = vv.w;
        sum += vv.x + vv.y + vv.z + vv.w;
    }
    ssc[t] = sum;
    __syncthreads();
    for (int d = 1; d < 256; d <<= 1) {
        int add = (t >= d) ? ssc[t - d] : 0;
        __syncthreads();
        ssc[t] += add;
        __syncthreads();
    }
    int run = (t == 0) ? 0 : ssc[t - 1];
#pragma unroll
    for (int j = 0; j < 32; ++j) {
        row_start[t * 32 + j] = run;
        cursor[t * 32 + j] = run;
        run += c[j];
    }
    if (t == 255) row_start[8192] = run;
}

// K_D: bucket edges by row; packed key (e<<13)|col; +2/16 fill.
__global__ void kD_scatter(const int* __restrict__ row, const int* __restrict__ col,
                           int* __restrict__ cursor, int* __restrict__ scol,
                           float4* __restrict__ zq) {
    int e = blockIdx.x * 256 + threadIdx.x;
    int r = row[e];
    int pos = atomicAdd(&cursor[r], 1);
    scol[pos] = (e << 13) | col[e];
    float4 z = make_float4(0.f, 0.f, 0.f, 0.f);
#pragma unroll
    for (int j = 0; j < 8; ++j)
        zq[Z_KD + e + (long long)j * ED] = z;
}

// K_E: agg[i] = sum_{edges of i} xw[col]; relu; u=agg@W1, v=agg@W2; +4/16 fill.
// 256-thread block = 2 independent 128-thread row groups (rows 2b, 2b+1).
__global__ __launch_bounds__(256) void kE_spmm_uv(const float* __restrict__ xw,
                                                  const int* __restrict__ row_start,
                                                  const int* __restrict__ scol,
                                                  const float* __restrict__ Wedge,
                                                  float* __restrict__ u,
                                                  float* __restrict__ v,
                                                  float4* __restrict__ zq) {
    int b = blockIdx.x, tid = threadIdx.x;
    int g = tid >> 7, t = tid & 127;
    int i = b * 2 + g;
    int s0 = row_start[i], s1 = row_start[i + 1];
    float acc = 0.f;
    int j = s0;
    for (; j + 4 <= s1; j += 4) {
        int c0 = scol[j] & 8191, c1 = scol[j + 1] & 8191;
        int c2 = scol[j + 2] & 8191, c3 = scol[j + 3] & 8191;
        float v0 = xw[(long long)c0 * HD + t];
        float v1 = xw[(long long)c1 * HD + t];
        float v2 = xw[(long long)c2 * HD + t];
        float v3 = xw[(long long)c3 * HD + t];
        acc += v0; acc += v1; acc += v2; acc += v3;
    }
    for (; j < s1; ++j) acc += xw[(long long)(scol[j] & 8191) * HD + t];
    acc = fmaxf(acc, 0.f);

    float up = acc * Wedge[t];
    float vp = acc * Wedge[HD + t];
#pragma unroll
    for (int off = 32; off > 0; off >>= 1) {
        up += __shfl_down(up, off);
        vp += __shfl_down(vp, off);
    }
    __shared__ float su[2][2], sv[2][2];
    int wid = t >> 6;       // wave within group
    if ((t & 63) == 0) { su[g][wid] = up; sv[g][wid] = vp; }
    __syncthreads();
    if (t == 0) { u[i] = su[g][0] + su[g][1]; v[i] = sv[g][0] + sv[g][1]; }

    // 4/16 of the dense adj zero-fill
    long long ft = (long long)b * 256 + tid;
    float4 z = make_float4(0.f, 0.f, 0.f, 0.f);
#pragma unroll
    for (int jj = 0; jj < 4; ++jj)
        zq[Z_KE + ft + (long long)jj * 1048576] = z;
}

// K_F: edge logits; +2/16 fill; per-block min/max partials; last block publishes lo/hi.
__global__ __launch_bounds__(256) void kF_elog(const int* __restrict__ row,
                                               const int* __restrict__ col,
                                               const float* __restrict__ u,
                                               const float* __restrict__ v,
                                               const float* __restrict__ b_edge,
                                               float* __restrict__ elog,
                                               float* __restrict__ pmn,
                                               float* __restrict__ pmx,
                                               unsigned* __restrict__ ctrl,
                                               float4* __restrict__ zq) {
    int gid = blockIdx.x * 256 + threadIdx.x;
    float el = u[row[gid]] + v[col[gid]] + b_edge[0];
    elog[gid] = el;

    float4 z = make_float4(0.f, 0.f, 0.f, 0.f);
#pragma unroll
    for (int j = 0; j < 8; ++j)
        zq[Z_KF + gid + (long long)j * ED] = z;

    float mn = el, mx = el;
#pragma unroll
    for (int off = 32; off > 0; off >>= 1) {
        mn = fminf(mn, __shfl_xor(mn, off));
        mx = fmaxf(mx, __shfl_xor(mx, off));
    }
    __shared__ float smn[4], smx[4];
    __shared__ unsigned tkt;
    int w = threadIdx.x >> 6;
    if ((threadIdx.x & 63) == 0) { smn[w] = mn; smx[w] = mx; }
    __syncthreads();
    if (threadIdx.x == 0) {
        pmn[blockIdx.x] = fminf(fminf(smn[0], smn[1]), fminf(smn[2], smn[3]));
        pmx[blockIdx.x] = fmaxf(fmaxf(smx[0], smx[1]), fmaxf(smx[2], smx[3]));
        __threadfence();
        tkt = atomicAdd(&ctrl[4], 1u);
    }
    __syncthreads();
    if (tkt == gridDim.x - 1) {
        __threadfence();
        int t = threadIdx.x;
        float4 a = ((const float4*)pmn)[t];
        float4 b = ((const float4*)pmx)[t];
        float m2 = fminf(fminf(a.x, a.y), fminf(a.z, a.w));
        float x2 = fmaxf(fmaxf(b.x, b.y), fmaxf(b.z, b.w));
#pragma unroll
        for (int off = 32; off > 0; off >>= 1) {
            m2 = fminf(m2, __shfl_xor(m2, off));
            x2 = fmaxf(x2, __shfl_xor(x2, off));
        }
        __shared__ float rmn[4], rmx[4];
        if ((t & 63) == 0) { rmn[t >> 6] = m2; rmx[t >> 6] = x2; }
        __syncthreads();
        if (t == 0) {
            float* flh = (float*)&ctrl[8];
            flh[0] = fminf(fminf(rmn[0], rmn[1]), fminf(rmn[2], rmn[3]));
            flh[1] = fmaxf(fmaxf(rmx[0], rmx[1]), fmaxf(rmx[2], rmx[3]));
        }
    }
}

// K_Z: parallel patch. Block b owns rows [8b, 8b+8) = contiguous CSR slice.
__global__ __launch_bounds__(256) void kZ_patch(const int* __restrict__ row_start,
                                                const int* __restrict__ scol,
                                                const float* __restrict__ elog,
                                                const float* __restrict__ noise,
                                                float* __restrict__ adj,
                                                int* __restrict__ pcu,
                                                int* __restrict__ pcz,
                                                unsigned* __restrict__ ctrl,
                                                float* __restrict__ rate) {
    const int tid = threadIdx.x;
    const int b = blockIdx.x;
    __shared__ int skey[1024];
    __shared__ int srs[9];
    if (tid < 9) srs[tid] = row_start[b * 8 + tid];
    __syncthreads();
    const int base = srs[0], n = srs[8] - base;
    for (int i = tid; i < n; i += 256) skey[i] = scol[base + i];
    __syncthreads();

    const float* flh = (const float*)&ctrl[8];
    const float lo = flh[0];
    const float hi = flh[1];
    const float kk = 0.3f / (hi - lo);          // ub=0.3, lb=0

    int uniq = 0, nzc = 0;
    for (int i = tid; i < n; i += 256) {
        int key = skey[i];
        int c = key & 8191;
        int p = base + i;
        int r = 0;
#pragma unroll
        for (int j = 1; j < 8; ++j) r += (p >= srs[j]) ? 1 : 0;
        int li = srs[r] - base, hiI = srs[r + 1] - base;
        // last-edge-wins: winner iff no same-col key with larger e in this row
        bool win = true;
        for (int j = li; j < hiI; ++j) {
            int kj = skey[j];
            if ((kj & 8191) == c && kj > key) { win = false; break; }
        }
        if (!win) continue;
        ++uniq;
        int e = key >> 13;
        float pr = kk * (elog[e] - lo);
        float lp = logf(pr + 1e-10f) - log1pf(1e-10f - pr);
        float nz = noise[(long long)(b * 8 + r) * NND + c];
        float lg = logf(nz) - log1pf(-nz);
        if ((lp + lg) <= 0.f) {                 // hard==0 -> adj cell = 1
            ++nzc;
            adj[(long long)(b * 8 + r) * NND + c] = 1.0f;
        }
    }

    // block reduce
#pragma unroll
    for (int off = 32; off > 0; off >>= 1) {
        uniq += __shfl_down(uniq, off);
        nzc  += __shfl_down(nzc, off);
    }
    __shared__ int scu[4], scz[4];
    __shared__ unsigned tkt;
    int wd = tid >> 6;
    if ((tid & 63) == 0) { scu[wd] = uniq; scz[wd] = nzc; }
    __syncthreads();
    if (tid == 0) {
        pcu[b] = scu[0] + scu[1] + scu[2] + scu[3];
        pcz[b] = scz[0] + scz[1] + scz[2] + scz[3];
        __threadfence();
        tkt = atomicAdd(&ctrl[5], 1u);
    }
    __syncthreads();
    if (tkt == gridDim.x - 1) {
        __threadfence();
        int t = tid;
        int4 a = ((const int4*)pcu)[t];
        int4 bq = ((const int4*)pcz)[t];
        int cu = a.x + a.y + a.z + a.w;
        int cz = bq.x + bq.y + bq.z + bq.w;
#pragma unroll
        for (int off = 32; off > 0; off >>= 1) {
            cu += __shfl_down(cu, off);
            cz += __shfl_down(cz, off);
        }
        __shared__ int rcu[4], rcz[4];
        if ((t & 63) == 0) { rcu[t >> 6] = cu; rcz[t >> 6] = cz; }
        __syncthreads();
        if (t == 0)
            rate[0] = (float)(rcz[0] + rcz[1] + rcz[2] + rcz[3]) /
                      (float)(rcu[0] + rcu[1] + rcu[2] + rcu[3]);
    }
}

extern "C" void kernel_launch(void* const* d_in, const int* in_sizes, int n_in,
                              void* d_out, int out_size, void* d_ws, size_t ws_size,
                              hipStream_t stream) {
    const float* x     = (const float*)d_in[0];
    const int*   row   = (const int*)d_in[1];
    const int*   col   = (const int*)d_in[2];
    const float* Wenc  = (const float*)d_in[3];
    const float* Wedge = (const float*)d_in[4];
    const float* bedge = (const float*)d_in[5];
    const float* noise = (const float*)d_in[6];
    const float* masku = (const float*)d_in[7];
    float* out = (float*)d_out;

    // workspace layout (~6.7 MB)
    char* ws = (char*)d_ws;
    float* xw        = (float*)(ws);                    // 4 MB
    float* elog      = (float*)(ws + 4194304);          // 1 MB
    float* u         = (float*)(ws + 5242880);          // 32 KB
    float* v         = (float*)(ws + 5275648);          // 32 KB
    int*   row_start = (int*)  (ws + 5308416);          // 36 KB reserve
    int*   cursor    = (int*)  (ws + 5345280);          // 32 KB
    int*   scol      = (int*)  (ws + 5378048);          // 1 MB
    int*   counts    = (int*)  (ws + 6426624);          // 32 KB
    unsigned* ctrl   = (unsigned*)(ws + 6721536);       // 64 B
    // partials alias buffers that are dead by the time they're used:
    float* pmn = (float*)cursor;            // cursor dead after kD
    float* pmx = pmn + 1024;
    int*   pcu = counts;                    // counts dead after kC
    int*   pcz = pcu + 1024;

    float4* zq  = (float4*)(out + NF_);
    float*  adj = out + NF_;
    float* rate = out + NF_ + NN_;

    k1_mega<<<1 + GEMMB + 1024, 256, 0, stream>>>(x, Wenc, masku, row, out, xw,
                                                  counts, ctrl);
    kC_scan<<<1, 256, 0, stream>>>(counts, row_start, cursor);
    kD_scatter<<<1024, 256, 0, stream>>>(row, col, cursor, scol, zq);
    kE_spmm_uv<<<4096, 256, 0, stream>>>(xw, row_start, scol, Wedge, u, v, zq);
    kF_elog<<<1024, 256, 0, stream>>>(row, col, u, v, bedge, elog, pmn, pmx, ctrl, zq);
    kZ_patch<<<1024, 256, 0, stream>>>(row_start, scol, elog, noise, adj,
                                       pcu, pcz, ctrl, rate);
}

// Round 9
// 248.732 us; speedup vs baseline: 1.1410x; 1.1410x over previous
//
#include <hip/hip_runtime.h>
#include <math.h>

// Problem constants
constexpr int NND = 8192;           // N nodes
constexpr int FD  = 512;            // features
constexpr int HD  = 128;            // hidden
constexpr int ED  = 262144;         // edges
constexpr long long NF_ = (long long)NND * FD;      // 4,194,304
constexpr long long NN_ = (long long)NND * NND;     // 67,108,864

// zero-fill quad partition of the dense adj region (units: float4 quads)
constexpr long long Z_K1 = 0;              // k1: 24 * 262144 = 6,291,456 (6/16)
constexpr long long Z_KD = 6291456;        // kD:  8 * 262144 = 2,097,152 (2/16)
constexpr long long Z_KE = 8388608;        // kE:  6 * 1048576 = 6,291,456 (6/16)
constexpr long long Z_KF = 14680064;       // kF:  8 * 262144 = 2,097,152 (ends 16,777,216)

constexpr int HISTB = 4;                   // histogram blocks 0..3
constexpr int GEMMB = 512;                 // GEMM blocks (16 rows each)
constexpr int GEMM_BASE = HISTB;           // bids [4, 516)
constexpr int FEAT_BASE = HISTB + GEMMB;   // feature blocks [516, 1540)

// ctrl words: [4]=ticketF, [5]=ticketZ, [8..9]=float lo/hi (written by kF)

// K1: blocks 0..3   = LDS histogram of row[] slice -> packed staging sector;
//     blocks 4..515 = fp32 GEMM xw = x@W_enc (16 rows, 2 rows/thread);
//     blocks 516+   = feature mask (4 quads/thread) + 6/16 adj fill.
__global__ __launch_bounds__(256) void k1_mega(const float* __restrict__ x,
                                               const float* __restrict__ W,
                                               const float* __restrict__ mask_u,
                                               const int* __restrict__ row,
                                               float* __restrict__ out,
                                               float* __restrict__ xw,
                                               int* __restrict__ stg) {
    __shared__ int hist[4096];      // 8192 packed 16-bit counters (16 KB)
    int tid = threadIdx.x;

    if (blockIdx.x < HISTB) {
        // ---- histogram block h: edges [h*65536, (h+1)*65536) ----
        int h = blockIdx.x;
#pragma unroll
        for (int j = 0; j < 16; ++j) hist[tid + j * 256] = 0;
        __syncthreads();
        const int4* rq = (const int4*)row + h * 16384;
        for (int it = 0; it < 8; ++it) {
            int4 r4[8];
#pragma unroll
            for (int j = 0; j < 8; ++j)
                r4[j] = rq[it * 2048 + j * 256 + tid];
#pragma unroll
            for (int j = 0; j < 8; ++j) {
                atomicAdd(&hist[r4[j].x >> 1], 1 << ((r4[j].x & 1) * 16));
                atomicAdd(&hist[r4[j].y >> 1], 1 << ((r4[j].y & 1) * 16));
                atomicAdd(&hist[r4[j].z >> 1], 1 << ((r4[j].z & 1) * 16));
                atomicAdd(&hist[r4[j].w >> 1], 1 << ((r4[j].w & 1) * 16));
            }
        }
        __syncthreads();
#pragma unroll
        for (int j = 0; j < 16; ++j)
            stg[h * 4096 + tid + j * 256] = hist[tid + j * 256];
    } else if (blockIdx.x < FEAT_BASE) {
        // ---- GEMM: block = 16 rows x 128 cols; thread = 2 rows x 4 cols ----
        int bid = blockIdx.x - GEMM_BASE;
        int tx = tid & 31, ty = tid >> 5;
        int m0 = bid * 16 + ty * 2;
        const float* xr0 = x + (long long)m0 * FD;
        const float* xr1 = xr0 + FD;
        float a0[4] = {0.f, 0.f, 0.f, 0.f};
        float a1[4] = {0.f, 0.f, 0.f, 0.f};
#pragma unroll 4
        for (int k = 0; k < FD; ++k) {
            float s0 = xr0[k], s1 = xr1[k];
            float4 b = *(const float4*)(W + k * HD + tx * 4);
            a0[0] = fmaf(s0, b.x, a0[0]);
            a0[1] = fmaf(s0, b.y, a0[1]);
            a0[2] = fmaf(s0, b.z, a0[2]);
            a0[3] = fmaf(s0, b.w, a0[3]);
            a1[0] = fmaf(s1, b.x, a1[0]);
            a1[1] = fmaf(s1, b.y, a1[1]);
            a1[2] = fmaf(s1, b.z, a1[2]);
            a1[3] = fmaf(s1, b.w, a1[3]);
        }
        *(float4*)(xw + (long long)m0 * HD + tx * 4) =
            make_float4(a0[0], a0[1], a0[2], a0[3]);
        *(float4*)(xw + (long long)(m0 + 1) * HD + tx * 4) =
            make_float4(a1[0], a1[1], a1[2], a1[3]);
    } else {
        int fid = (blockIdx.x - FEAT_BASE) * 256 + tid;   // 0 .. 262143
        // column-quad = fid & 127 (stride 262144 is a multiple of 128)
        int c4 = (fid & 127) * 4;
        float kx = (mask_u[c4 + 0] < 0.2f) ? 0.f : 1.f;
        float ky = (mask_u[c4 + 1] < 0.2f) ? 0.f : 1.f;
        float kz = (mask_u[c4 + 2] < 0.2f) ? 0.f : 1.f;
        float kw = (mask_u[c4 + 3] < 0.2f) ? 0.f : 1.f;
        const float4* xq = (const float4*)x;
        float4* oq = (float4*)out;
#pragma unroll
        for (int j = 0; j < 4; ++j) {
            long long q = fid + (long long)j * 262144;
            float4 xv = xq[q];
            float4 o;
            o.x = xv.x * kx; o.y = xv.y * ky; o.z = xv.z * kz; o.w = xv.w * kw;
            oq[q] = o;
        }
        // 6/16 of the dense adj zero-fill
        float4* zq = (float4*)(out + NF_);
        float4 z = make_float4(0.f, 0.f, 0.f, 0.f);
#pragma unroll
        for (int j = 0; j < 24; ++j)
            zq[Z_K1 + fid + (long long)j * 262144] = z;
    }
}

// K_C: merge 4 packed sectors, exclusive scan -> row_start[N+1], cursor[N];
// also init ctrl. 1 block / 256 threads.
__global__ __launch_bounds__(256) void kC_scan(const int* __restrict__ stg,
                                               int* __restrict__ row_start,
                                               int* __restrict__ cursor,
                                               unsigned* __restrict__ ctrl) {
    __shared__ int ssc[256];
    int t = threadIdx.x;
    if (t < 16) ctrl[t] = 0u;
    int c[32];
    int sum = 0;
#pragma unroll
    for (int j = 0; j < 16; ++j) {
        // packed add across sectors is exact (per-field sums << 2^16)
        int pv = stg[t * 16 + j] + stg[4096 + t * 16 + j] +
                 stg[8192 + t * 16 + j] + stg[12288 + t * 16 + j];
        int lo = pv & 0xFFFF, hi = ((unsigned)pv) >> 16;
        c[2 * j] = lo; c[2 * j + 1] = hi;
        sum += lo + hi;
    }
    ssc[t] = sum;
    __syncthreads();
    for (int d = 1; d < 256; d <<= 1) {
        int add = (t >= d) ? ssc[t - d] : 0;
        __syncthreads();
        ssc[t] += add;
        __syncthreads();
    }
    int run = (t == 0) ? 0 : ssc[t - 1];
#pragma unroll
    for (int j = 0; j < 32; ++j) {
        row_start[t * 32 + j] = run;
        cursor[t * 32 + j] = run;
        run += c[j];
    }
    if (t == 255) row_start[8192] = run;
}

// K_D: bucket edges by row; packed key (e<<13)|col; +2/16 fill.
__global__ void kD_scatter(const int* __restrict__ row, const int* __restrict__ col,
                           int* __restrict__ cursor, int* __restrict__ scol,
                           float4* __restrict__ zq) {
    int e = blockIdx.x * 256 + threadIdx.x;
    int r = row[e];
    int pos = atomicAdd(&cursor[r], 1);
    scol[pos] = (e << 13) | col[e];
    float4 z = make_float4(0.f, 0.f, 0.f, 0.f);
#pragma unroll
    for (int j = 0; j < 8; ++j)
        zq[Z_KD + e + (long long)j * ED] = z;
}

// K_E: agg[i] = sum_{edges of i} xw[col]; relu; u=agg@W1, v=agg@W2; +6/16 fill.
__global__ __launch_bounds__(128) void kE_spmm_uv(const float* __restrict__ xw,
                                                  const int* __restrict__ row_start,
                                                  const int* __restrict__ scol,
                                                  const float* __restrict__ Wedge,
                                                  float* __restrict__ u,
                                                  float* __restrict__ v,
                                                  float4* __restrict__ zq) {
    int i = blockIdx.x, t = threadIdx.x;
    int s0 = row_start[i], s1 = row_start[i + 1];
    float acc = 0.f;
    int j = s0;
    for (; j + 4 <= s1; j += 4) {
        int c0 = scol[j] & 8191, c1 = scol[j + 1] & 8191;
        int c2 = scol[j + 2] & 8191, c3 = scol[j + 3] & 8191;
        float v0 = xw[(long long)c0 * HD + t];
        float v1 = xw[(long long)c1 * HD + t];
        float v2 = xw[(long long)c2 * HD + t];
        float v3 = xw[(long long)c3 * HD + t];
        acc += v0; acc += v1; acc += v2; acc += v3;
    }
    for (; j < s1; ++j) acc += xw[(long long)(scol[j] & 8191) * HD + t];
    acc = fmaxf(acc, 0.f);

    float up = acc * Wedge[t];
    float vp = acc * Wedge[HD + t];
#pragma unroll
    for (int off = 32; off > 0; off >>= 1) {
        up += __shfl_down(up, off);
        vp += __shfl_down(vp, off);
    }
    __shared__ float su[2], sv[2];
    int wid = t >> 6;
    if ((t & 63) == 0) { su[wid] = up; sv[wid] = vp; }
    __syncthreads();
    if (t == 0) { u[i] = su[0] + su[1]; v[i] = sv[0] + sv[1]; }

    // 6/16 of the dense adj zero-fill
    long long ft = (long long)i * 128 + t;
    float4 z = make_float4(0.f, 0.f, 0.f, 0.f);
#pragma unroll
    for (int jj = 0; jj < 6; ++jj)
        zq[Z_KE + ft + (long long)jj * 1048576] = z;
}

// K_F: edge logits; +2/16 fill; per-block min/max partials; last block publishes lo/hi.
__global__ __launch_bounds__(256) void kF_elog(const int* __restrict__ row,
                                               const int* __restrict__ col,
                                               const float* __restrict__ u,
                                               const float* __restrict__ v,
                                               const float* __restrict__ b_edge,
                                               float* __restrict__ elog,
                                               float* __restrict__ pmn,
                                               float* __restrict__ pmx,
                                               unsigned* __restrict__ ctrl,
                                               float4* __restrict__ zq) {
    int gid = blockIdx.x * 256 + threadIdx.x;
    float el = u[row[gid]] + v[col[gid]] + b_edge[0];
    elog[gid] = el;

    float4 z = make_float4(0.f, 0.f, 0.f, 0.f);
#pragma unroll
    for (int j = 0; j < 8; ++j)
        zq[Z_KF + gid + (long long)j * ED] = z;

    float mn = el, mx = el;
#pragma unroll
    for (int off = 32; off > 0; off >>= 1) {
        mn = fminf(mn, __shfl_xor(mn, off));
        mx = fmaxf(mx, __shfl_xor(mx, off));
    }
    __shared__ float smn[4], smx[4];
    __shared__ unsigned tkt;
    int w = threadIdx.x >> 6;
    if ((threadIdx.x & 63) == 0) { smn[w] = mn; smx[w] = mx; }
    __syncthreads();
    if (threadIdx.x == 0) {
        pmn[blockIdx.x] = fminf(fminf(smn[0], smn[1]), fminf(smn[2], smn[3]));
        pmx[blockIdx.x] = fmaxf(fmaxf(smx[0], smx[1]), fmaxf(smx[2], smx[3]));
        __threadfence();
        tkt = atomicAdd(&ctrl[4], 1u);
    }
    __syncthreads();
    if (tkt == gridDim.x - 1) {
        __threadfence();
        int t = threadIdx.x;
        float4 a = ((const float4*)pmn)[t];
        float4 b = ((const float4*)pmx)[t];
        float m2 = fminf(fminf(a.x, a.y), fminf(a.z, a.w));
        float x2 = fmaxf(fmaxf(b.x, b.y), fmaxf(b.z, b.w));
#pragma unroll
        for (int off = 32; off > 0; off >>= 1) {
            m2 = fminf(m2, __shfl_xor(m2, off));
            x2 = fmaxf(x2, __shfl_xor(x2, off));
        }
        __shared__ float rmn[4], rmx[4];
        if ((t & 63) == 0) { rmn[t >> 6] = m2; rmx[t >> 6] = x2; }
        __syncthreads();
        if (t == 0) {
            float* flh = (float*)&ctrl[8];
            flh[0] = fminf(fminf(rmn[0], rmn[1]), fminf(rmn[2], rmn[3]));
            flh[1] = fmaxf(fmaxf(rmx[0], rmx[1]), fmaxf(rmx[2], rmx[3]));
        }
    }
}

// K_Z: parallel patch. Block b owns rows [8b, 8b+8) = contiguous CSR slice.
__global__ __launch_bounds__(256) void kZ_patch(const int* __restrict__ row_start,
                                                const int* __restrict__ scol,
                                                const float* __restrict__ elog,
                                                const float* __restrict__ noise,
                                                float* __restrict__ adj,
                                                int* __restrict__ pcu,
                                                int* __restrict__ pcz,
                                                unsigned* __restrict__ ctrl,
                                                float* __restrict__ rate) {
    const int tid = threadIdx.x;
    const int b = blockIdx.x;
    __shared__ int skey[1024];
    __shared__ int srs[9];
    if (tid < 9) srs[tid] = row_start[b * 8 + tid];
    __syncthreads();
    const int base = srs[0], n = srs[8] - base;
    for (int i = tid; i < n; i += 256) skey[i] = scol[base + i];
    __syncthreads();

    const float* flh = (const float*)&ctrl[8];
    const float lo = flh[0];
    const float hi = flh[1];
    const float kk = 0.3f / (hi - lo);          // ub=0.3, lb=0

    int uniq = 0, nzc = 0;
    for (int i = tid; i < n; i += 256) {
        int key = skey[i];
        int c = key & 8191;
        int p = base + i;
        int r = 0;
#pragma unroll
        for (int j = 1; j < 8; ++j) r += (p >= srs[j]) ? 1 : 0;
        int li = srs[r] - base, hiI = srs[r + 1] - base;
        // last-edge-wins: winner iff no same-col key with larger e in this row
        bool win = true;
        for (int j = li; j < hiI; ++j) {
            int kj = skey[j];
            if ((kj & 8191) == c && kj > key) { win = false; break; }
        }
        if (!win) continue;
        ++uniq;
        int e = key >> 13;
        float pr = kk * (elog[e] - lo);
        float lp = logf(pr + 1e-10f) - log1pf(1e-10f - pr);
        float nz = noise[(long long)(b * 8 + r) * NND + c];
        float lg = logf(nz) - log1pf(-nz);
        if ((lp + lg) <= 0.f) {                 // hard==0 -> adj cell = 1
            ++nzc;
            adj[(long long)(b * 8 + r) * NND + c] = 1.0f;
        }
    }

    // block reduce
#pragma unroll
    for (int off = 32; off > 0; off >>= 1) {
        uniq += __shfl_down(uniq, off);
        nzc  += __shfl_down(nzc, off);
    }
    __shared__ int scu[4], scz[4];
    __shared__ unsigned tkt;
    int wd = tid >> 6;
    if ((tid & 63) == 0) { scu[wd] = uniq; scz[wd] = nzc; }
    __syncthreads();
    if (tid == 0) {
        pcu[b] = scu[0] + scu[1] + scu[2] + scu[3];
        pcz[b] = scz[0] + scz[1] + scz[2] + scz[3];
        __threadfence();
        tkt = atomicAdd(&ctrl[5], 1u);
    }
    __syncthreads();
    if (tkt == gridDim.x - 1) {
        __threadfence();
        int t = tid;
        int4 a = ((const int4*)pcu)[t];
        int4 bq = ((const int4*)pcz)[t];
        int cu = a.x + a.y + a.z + a.w;
        int cz = bq.x + bq.y + bq.z + bq.w;
#pragma unroll
        for (int off = 32; off > 0; off >>= 1) {
            cu += __shfl_down(cu, off);
            cz += __shfl_down(cz, off);
        }
        __shared__ int rcu[4], rcz[4];
        if ((t & 63) == 0) { rcu[t >> 6] = cu; rcz[t >> 6] = cz; }
        __syncthreads();
        if (t == 0)
            rate[0] = (float)(rcz[0] + rcz[1] + rcz[2] + rcz[3]) /
                      (float)(rcu[0] + rcu[1] + rcu[2] + rcu[3]);
    }
}

extern "C" void kernel_launch(void* const* d_in, const int* in_sizes, int n_in,
                              void* d_out, int out_size, void* d_ws, size_t ws_size,
                              hipStream_t stream) {
    const float* x     = (const float*)d_in[0];
    const int*   row   = (const int*)d_in[1];
    const int*   col   = (const int*)d_in[2];
    const float* Wenc  = (const float*)d_in[3];
    const float* Wedge = (const float*)d_in[4];
    const float* bedge = (const float*)d_in[5];
    const float* noise = (const float*)d_in[6];
    const float* masku = (const float*)d_in[7];
    float* out = (float*)d_out;

    // workspace layout (~6.7 MB)
    char* ws = (char*)d_ws;
    float* xw        = (float*)(ws);                    // 4 MB
    float* elog      = (float*)(ws + 4194304);          // 1 MB
    float* u         = (float*)(ws + 5242880);          // 32 KB
    float* v         = (float*)(ws + 5275648);          // 32 KB
    int*   row_start = (int*)  (ws + 5308416);          // 36 KB reserve
    int*   cursor    = (int*)  (ws + 5345280);          // 32 KB
    int*   scol      = (int*)  (ws + 5378048);          // 1 MB, ends 6426624
    int*   pc        = (int*)  (ws + 6426624);          // 32 KB (kZ partials)
    int*   stg       = (int*)  (ws + 6459392);          // 64 KB packed hist sectors
    unsigned* ctrl   = (unsigned*)(ws + 6721536);       // 64 B
    // partials alias buffers that are dead by the time they're used:
    float* pmn = (float*)cursor;            // cursor dead after kD
    float* pmx = pmn + 1024;
    int*   pcu = pc;
    int*   pcz = pcu + 1024;

    float4* zq  = (float4*)(out + NF_);
    float*  adj = out + NF_;
    float* rate = out + NF_ + NN_;

    k1_mega<<<HISTB + GEMMB + 1024, 256, 0, stream>>>(x, Wenc, masku, row, out,
                                                      xw, stg);
    kC_scan<<<1, 256, 0, stream>>>(stg, row_start, cursor, ctrl);
    kD_scatter<<<1024, 256, 0, stream>>>(row, col, cursor, scol, zq);
    kE_spmm_uv<<<8192, 128, 0, stream>>>(xw, row_start, scol, Wedge, u, v, zq);
    kF_elog<<<1024, 256, 0, stream>>>(row, col, u, v, bedge, elog, pmn, pmx, ctrl, zq);
    kZ_patch<<<1024, 256, 0, stream>>>(row_start, scol, elog, noise, adj,
                                       pcu, pcz, ctrl, rate);
}

// Round 10
// 245.430 us; speedup vs baseline: 1.1564x; 1.0135x over previous
//
#include <hip/hip_runtime.h>
#include <math.h>

// Problem constants
constexpr int NND = 8192;           // N nodes
constexpr int FD  = 512;            // features
constexpr int HD  = 128;            // hidden
constexpr int ED  = 262144;         // edges
constexpr long long NF_ = (long long)NND * FD;      // 4,194,304
constexpr long long NN_ = (long long)NND * NND;     // 67,108,864

constexpr int SLOT = 72;            // bucket capacity; max row count ~56 (7-sigma)

// zero-fill quad partition of the dense adj region (units: float4 quads)
constexpr long long Z_K1 = 0;              // feature blocks: 24*262144 = 6,291,456 (6/16)
constexpr long long Z_KD = 6291456;        // scatter blocks:  8*262144 = 2,097,152 (2/16)
constexpr long long Z_KE = 8388608;        // kE: 6*1048576 = 6,291,456 (6/16)
constexpr long long Z_KF = 14680064;       // kF: 8*262144 = 2,097,152 (ends 16,777,216)

constexpr int GEMMB = 512;                 // GEMM blocks [0,512)
constexpr int SCAT_BASE = GEMMB;           // scatter blocks [512,1536)
constexpr int FEAT_BASE = GEMMB + 1024;    // feature blocks [1536,2560)

// ctrl words: [4]=ticketF, [5]=ticketZ, [8..9]=float lo/hi (written by kF)

// K0: zero cnt + ctrl.
__global__ void k0_init(int* __restrict__ cnt, unsigned* __restrict__ ctrl) {
    int t = blockIdx.x * 256 + threadIdx.x;
    if (t < NND) cnt[t] = 0;
    if (t < 16) ctrl[t] = 0u;
}

// K1: blocks [0,512)     = fp32 GEMM xw = x@W_enc (16 rows, 2 rows/thread);
//     blocks [512,1536)  = edge scatter into row buckets + 2/16 adj fill;
//     blocks [1536,2560) = feature mask (4 quads/thread) + 6/16 adj fill.
__global__ __launch_bounds__(256) void k1_mega(const float* __restrict__ x,
                                               const float* __restrict__ W,
                                               const float* __restrict__ mask_u,
                                               const int* __restrict__ row,
                                               const int* __restrict__ col,
                                               float* __restrict__ out,
                                               float* __restrict__ xw,
                                               int* __restrict__ cnt,
                                               int* __restrict__ slot) {
    int tid = threadIdx.x;
    if (blockIdx.x < GEMMB) {
        // ---- GEMM: block = 16 rows x 128 cols; thread = 2 rows x 4 cols ----
        int bid = blockIdx.x;
        int tx = tid & 31, ty = tid >> 5;
        int m0 = bid * 16 + ty * 2;
        const float* xr0 = x + (long long)m0 * FD;
        const float* xr1 = xr0 + FD;
        float a0[4] = {0.f, 0.f, 0.f, 0.f};
        float a1[4] = {0.f, 0.f, 0.f, 0.f};
#pragma unroll 4
        for (int k = 0; k < FD; ++k) {
            float s0 = xr0[k], s1 = xr1[k];
            float4 b = *(const float4*)(W + k * HD + tx * 4);
            a0[0] = fmaf(s0, b.x, a0[0]);
            a0[1] = fmaf(s0, b.y, a0[1]);
            a0[2] = fmaf(s0, b.z, a0[2]);
            a0[3] = fmaf(s0, b.w, a0[3]);
            a1[0] = fmaf(s1, b.x, a1[0]);
            a1[1] = fmaf(s1, b.y, a1[1]);
            a1[2] = fmaf(s1, b.z, a1[2]);
            a1[3] = fmaf(s1, b.w, a1[3]);
        }
        *(float4*)(xw + (long long)m0 * HD + tx * 4) =
            make_float4(a0[0], a0[1], a0[2], a0[3]);
        *(float4*)(xw + (long long)(m0 + 1) * HD + tx * 4) =
            make_float4(a1[0], a1[1], a1[2], a1[3]);
    } else if (blockIdx.x < FEAT_BASE) {
        // ---- scatter: one edge per thread into its row bucket; +2/16 fill ----
        int e = (blockIdx.x - SCAT_BASE) * 256 + tid;   // 0 .. 262143
        int r = row[e];
        int pos = atomicAdd(&cnt[r], 1);
        slot[r * SLOT + pos] = (e << 13) | col[e];
        float4* zq = (float4*)(out + NF_);
        float4 z = make_float4(0.f, 0.f, 0.f, 0.f);
#pragma unroll
        for (int j = 0; j < 8; ++j)
            zq[Z_KD + e + (long long)j * ED] = z;
    } else {
        int fid = (blockIdx.x - FEAT_BASE) * 256 + tid;   // 0 .. 262143
        // column-quad = fid & 127 (stride 262144 is a multiple of 128)
        int c4 = (fid & 127) * 4;
        float kx = (mask_u[c4 + 0] < 0.2f) ? 0.f : 1.f;
        float ky = (mask_u[c4 + 1] < 0.2f) ? 0.f : 1.f;
        float kz = (mask_u[c4 + 2] < 0.2f) ? 0.f : 1.f;
        float kw = (mask_u[c4 + 3] < 0.2f) ? 0.f : 1.f;
        const float4* xq = (const float4*)x;
        float4* oq = (float4*)out;
#pragma unroll
        for (int j = 0; j < 4; ++j) {
            long long q = fid + (long long)j * 262144;
            float4 xv = xq[q];
            float4 o;
            o.x = xv.x * kx; o.y = xv.y * ky; o.z = xv.z * kz; o.w = xv.w * kw;
            oq[q] = o;
        }
        // 6/16 of the dense adj zero-fill
        float4* zq = (float4*)(out + NF_);
        float4 z = make_float4(0.f, 0.f, 0.f, 0.f);
#pragma unroll
        for (int j = 0; j < 24; ++j)
            zq[Z_K1 + fid + (long long)j * 262144] = z;
    }
}

// K_E: agg[i] = sum over bucket(i) of xw[col]; relu; u=agg@W1, v=agg@W2; +6/16 fill.
__global__ __launch_bounds__(128) void kE_spmm_uv(const float* __restrict__ xw,
                                                  const int* __restrict__ cnt,
                                                  const int* __restrict__ slot,
                                                  const float* __restrict__ Wedge,
                                                  float* __restrict__ u,
                                                  float* __restrict__ v,
                                                  float4* __restrict__ zq) {
    int i = blockIdx.x, t = threadIdx.x;
    int n = cnt[i];
    const int* sp = slot + i * SLOT;
    float acc = 0.f;
    int j = 0;
    for (; j + 4 <= n; j += 4) {
        int c0 = sp[j] & 8191, c1 = sp[j + 1] & 8191;
        int c2 = sp[j + 2] & 8191, c3 = sp[j + 3] & 8191;
        float v0 = xw[(long long)c0 * HD + t];
        float v1 = xw[(long long)c1 * HD + t];
        float v2 = xw[(long long)c2 * HD + t];
        float v3 = xw[(long long)c3 * HD + t];
        acc += v0; acc += v1; acc += v2; acc += v3;
    }
    for (; j < n; ++j) acc += xw[(long long)(sp[j] & 8191) * HD + t];
    acc = fmaxf(acc, 0.f);

    float up = acc * Wedge[t];
    float vp = acc * Wedge[HD + t];
#pragma unroll
    for (int off = 32; off > 0; off >>= 1) {
        up += __shfl_down(up, off);
        vp += __shfl_down(vp, off);
    }
    __shared__ float su[2], sv[2];
    int wid = t >> 6;
    if ((t & 63) == 0) { su[wid] = up; sv[wid] = vp; }
    __syncthreads();
    if (t == 0) { u[i] = su[0] + su[1]; v[i] = sv[0] + sv[1]; }

    // 6/16 of the dense adj zero-fill
    long long ft = (long long)i * 128 + t;
    float4 z = make_float4(0.f, 0.f, 0.f, 0.f);
#pragma unroll
    for (int jj = 0; jj < 6; ++jj)
        zq[Z_KE + ft + (long long)jj * 1048576] = z;
}

// K_F: edge-logit min/max only (logits recomputed later, never stored);
// +2/16 fill; per-block partials; last block publishes lo/hi to ctrl[8..9].
__global__ __launch_bounds__(256) void kF_minmax(const int* __restrict__ row,
                                                 const int* __restrict__ col,
                                                 const float* __restrict__ u,
                                                 const float* __restrict__ v,
                                                 const float* __restrict__ b_edge,
                                                 float* __restrict__ pmn,
                                                 float* __restrict__ pmx,
                                                 unsigned* __restrict__ ctrl,
                                                 float4* __restrict__ zq) {
    int gid = blockIdx.x * 256 + threadIdx.x;
    float el = u[row[gid]] + v[col[gid]] + b_edge[0];

    float4 z = make_float4(0.f, 0.f, 0.f, 0.f);
#pragma unroll
    for (int j = 0; j < 8; ++j)
        zq[Z_KF + gid + (long long)j * ED] = z;

    float mn = el, mx = el;
#pragma unroll
    for (int off = 32; off > 0; off >>= 1) {
        mn = fminf(mn, __shfl_xor(mn, off));
        mx = fmaxf(mx, __shfl_xor(mx, off));
    }
    __shared__ float smn[4], smx[4];
    __shared__ unsigned tkt;
    int w = threadIdx.x >> 6;
    if ((threadIdx.x & 63) == 0) { smn[w] = mn; smx[w] = mx; }
    __syncthreads();
    if (threadIdx.x == 0) {
        pmn[blockIdx.x] = fminf(fminf(smn[0], smn[1]), fminf(smn[2], smn[3]));
        pmx[blockIdx.x] = fmaxf(fmaxf(smx[0], smx[1]), fmaxf(smx[2], smx[3]));
        __threadfence();
        tkt = atomicAdd(&ctrl[4], 1u);
    }
    __syncthreads();
    if (tkt == gridDim.x - 1) {
        __threadfence();
        int t = threadIdx.x;
        float4 a = ((const float4*)pmn)[t];
        float4 b = ((const float4*)pmx)[t];
        float m2 = fminf(fminf(a.x, a.y), fminf(a.z, a.w));
        float x2 = fmaxf(fmaxf(b.x, b.y), fmaxf(b.z, b.w));
#pragma unroll
        for (int off = 32; off > 0; off >>= 1) {
            m2 = fminf(m2, __shfl_xor(m2, off));
            x2 = fmaxf(x2, __shfl_xor(x2, off));
        }
        __shared__ float rmn[4], rmx[4];
        if ((t & 63) == 0) { rmn[t >> 6] = m2; rmx[t >> 6] = x2; }
        __syncthreads();
        if (t == 0) {
            float* flh = (float*)&ctrl[8];
            flh[0] = fminf(fminf(rmn[0], rmn[1]), fminf(rmn[2], rmn[3]));
            flh[1] = fmaxf(fmaxf(rmx[0], rmx[1]), fmaxf(rmx[2], rmx[3]));
        }
    }
}

// K_Z: parallel patch. Block b owns rows [8b, 8b+8); per-row buckets in LDS;
// last-edge-wins; el recomputed as u[r]+v[c]+b (bit-identical to kF's form).
__global__ __launch_bounds__(256) void kZ_patch(const int* __restrict__ cnt,
                                                const int* __restrict__ slot,
                                                const float* __restrict__ u,
                                                const float* __restrict__ v,
                                                const float* __restrict__ b_edge,
                                                const float* __restrict__ noise,
                                                float* __restrict__ adj,
                                                int* __restrict__ pcu,
                                                int* __restrict__ pcz,
                                                unsigned* __restrict__ ctrl,
                                                float* __restrict__ rate) {
    const int tid = threadIdx.x;
    const int b = blockIdx.x;
    __shared__ int skey[8 * SLOT];
    __shared__ int scnt[8];
    __shared__ float su_[8];
    if (tid < 8) {
        scnt[tid] = cnt[b * 8 + tid];
        su_[tid] = u[b * 8 + tid];
    }
    __syncthreads();
#pragma unroll
    for (int rl = 0; rl < 8; ++rl) {
        int n = scnt[rl];
        for (int i = tid; i < n; i += 256)
            skey[rl * SLOT + i] = slot[(b * 8 + rl) * SLOT + i];
    }
    __syncthreads();

    const float* flh = (const float*)&ctrl[8];
    const float lo = flh[0];
    const float hi = flh[1];
    const float kk = 0.3f / (hi - lo);          // ub=0.3, lb=0
    const float be = b_edge[0];

    int uniq = 0, nzc = 0;
#pragma unroll
    for (int rl = 0; rl < 8; ++rl) {
        int n = scnt[rl];
        const int* kp = skey + rl * SLOT;
        for (int i = tid; i < n; i += 256) {
            int key = kp[i];
            int c = key & 8191;
            // last-edge-wins: winner iff no same-col key with larger e in this row
            bool win = true;
            for (int j = 0; j < n; ++j) {
                int kj = kp[j];
                if ((kj & 8191) == c && kj > key) { win = false; break; }
            }
            if (!win) continue;
            ++uniq;
            float el = su_[rl] + v[c] + be;     // == kF's logit, bit-identical
            float pr = kk * (el - lo);
            float lp = logf(pr + 1e-10f) - log1pf(1e-10f - pr);
            float nz = noise[(long long)(b * 8 + rl) * NND + c];
            float lg = logf(nz) - log1pf(-nz);
            if ((lp + lg) <= 0.f) {             // hard==0 -> adj cell = 1
                ++nzc;
                adj[(long long)(b * 8 + rl) * NND + c] = 1.0f;
            }
        }
    }

    // block reduce
#pragma unroll
    for (int off = 32; off > 0; off >>= 1) {
        uniq += __shfl_down(uniq, off);
        nzc  += __shfl_down(nzc, off);
    }
    __shared__ int scu[4], scz[4];
    __shared__ unsigned tkt;
    int wd = tid >> 6;
    if ((tid & 63) == 0) { scu[wd] = uniq; scz[wd] = nzc; }
    __syncthreads();
    if (tid == 0) {
        pcu[b] = scu[0] + scu[1] + scu[2] + scu[3];
        pcz[b] = scz[0] + scz[1] + scz[2] + scz[3];
        __threadfence();
        tkt = atomicAdd(&ctrl[5], 1u);
    }
    __syncthreads();
    if (tkt == gridDim.x - 1) {
        __threadfence();
        int t = tid;
        int4 a = ((const int4*)pcu)[t];
        int4 bq = ((const int4*)pcz)[t];
        int cu = a.x + a.y + a.z + a.w;
        int cz = bq.x + bq.y + bq.z + bq.w;
#pragma unroll
        for (int off = 32; off > 0; off >>= 1) {
            cu += __shfl_down(cu, off);
            cz += __shfl_down(cz, off);
        }
        __shared__ int rcu[4], rcz[4];
        if ((t & 63) == 0) { rcu[t >> 6] = cu; rcz[t >> 6] = cz; }
        __syncthreads();
        if (t == 0)
            rate[0] = (float)(rcz[0] + rcz[1] + rcz[2] + rcz[3]) /
                      (float)(rcu[0] + rcu[1] + rcu[2] + rcu[3]);
    }
}

extern "C" void kernel_launch(void* const* d_in, const int* in_sizes, int n_in,
                              void* d_out, int out_size, void* d_ws, size_t ws_size,
                              hipStream_t stream) {
    const float* x     = (const float*)d_in[0];
    const int*   row   = (const int*)d_in[1];
    const int*   col   = (const int*)d_in[2];
    const float* Wenc  = (const float*)d_in[3];
    const float* Wedge = (const float*)d_in[4];
    const float* bedge = (const float*)d_in[5];
    const float* noise = (const float*)d_in[6];
    const float* masku = (const float*)d_in[7];
    float* out = (float*)d_out;

    // workspace layout (~6.67 MB, within the proven 6.72 MB budget)
    char* ws = (char*)d_ws;
    float* xw   = (float*)(ws);                 // 4,194,304 B
    int*   slot = (int*)  (ws + 4194304);       // 8192*72*4 = 2,359,296 B
    float* u    = (float*)(ws + 6553600);       // 32 KB
    float* v    = (float*)(ws + 6586368);       // 32 KB
    int*   cnt  = (int*)  (ws + 6619136);       // 32 KB
    int*   pcu  = (int*)  (ws + 6651904);       // 4 KB
    int*   pcz  = (int*)  (ws + 6656000);       // 4 KB
    float* pmn  = (float*)(ws + 6660096);       // 4 KB
    float* pmx  = (float*)(ws + 6664192);       // 4 KB
    unsigned* ctrl = (unsigned*)(ws + 6668288); // 64 B

    float4* zq  = (float4*)(out + NF_);
    float*  adj = out + NF_;
    float* rate = out + NF_ + NN_;

    k0_init<<<32, 256, 0, stream>>>(cnt, ctrl);
    k1_mega<<<GEMMB + 1024 + 1024, 256, 0, stream>>>(x, Wenc, masku, row, col,
                                                     out, xw, cnt, slot);
    kE_spmm_uv<<<8192, 128, 0, stream>>>(xw, cnt, slot, Wedge, u, v, zq);
    kF_minmax<<<1024, 256, 0, stream>>>(row, col, u, v, bedge, pmn, pmx, ctrl, zq);
    kZ_patch<<<1024, 256, 0, stream>>>(cnt, slot, u, v, bedge, noise, adj,
                                       pcu, pcz, ctrl, rate);
}